// Round 2
// baseline (2121.410 us; speedup 1.0000x reference)
//
#include <hip/hip_runtime.h>

typedef unsigned short u16;
typedef unsigned int u32;

typedef __attribute__((ext_vector_type(4))) float floatx4;
typedef __attribute__((ext_vector_type(8))) __bf16 bf16x8;

typedef __attribute__((address_space(3))) u32 lds_u32_t;
typedef __attribute__((address_space(1))) u32 glb_u32_t;

__device__ __forceinline__ void gld_lds16(const u16* g, u16* l) {
    __builtin_amdgcn_global_load_lds((glb_u32_t*)g, (lds_u32_t*)l, 16, 0, 0);
}

__device__ __forceinline__ u16 f2bf(float f) {
    u32 u = __float_as_uint(f);
    u += 0x7fffu + ((u >> 16) & 1u);
    return (u16)(u >> 16);
}
// pack two fp32 -> two bf16 (RNE) in one u32
__device__ __forceinline__ u32 pk2(float a, float b) {
    u32 x = __float_as_uint(a), y = __float_as_uint(b);
    x += 0x7fffu + ((x >> 16) & 1u);
    y += 0x7fffu + ((y >> 16) & 1u);
    return (x >> 16) | (y & 0xffff0000u);
}

// raw barrier: no vmcnt drain (the whole point of the counted pipeline);
// "memory" clobber pins all compiler-visible memory ops to their phase.
#define BARRIER() asm volatile("s_barrier" ::: "memory")
#define WAITVM(N) asm volatile("s_waitcnt vmcnt(" #N ")" ::: "memory")
// st_16x32 swizzle (m201): flip byte-bit5 by byte-bit9, within each 16KB half
#define SWZ(d) ((d) ^ ((((d) >> 9) & 1) << 5))
#define MFMA16(a, b, c) __builtin_amdgcn_mfma_f32_16x16x32_bf16(a, b, c, 0, 0, 0)

// Stage one 16KB half-tile (128 rows x 64 cols bf16) g->LDS via global_load_lds.
// LDS dest is linear (wave-uniform base + lane*16); the st_16x32 permutation is
// applied by pre-swizzling the per-lane GLOBAL source chunk (involution).
__device__ __forceinline__ void stage_half(const u16* __restrict__ g, int ld,
                                           u16* halfdst, int wid, int lane)
{
#pragma unroll
    for (int j = 0; j < 2; ++j) {
        const int clin = wid * 128 + j * 64 + lane;          // 16B chunk in half
        const int csrc = clin ^ (((clin >> 5) & 1) << 1);    // chunk-level SWZ
        gld_lds16(g + (size_t)(csrc >> 3) * ld + (csrc & 7) * 8,
                  halfdst + clin * 8);
    }
}

// ===================== 256x256 8-phase GEMM (m201 template) =====================
// C = A[M,K](bf16) @ Bt[N,K]^T(bf16) + bias;  EPI==0: C bf16;  EPI==1: C f32 += R
// 512 thr = 8 waves (2M x 4N); per-wave out 128x64; BK=64, 2 K-tiles/iter;
// LDS 128KB = 2 bufs x (A 32KB | B 32KB), halves of 16KB each.
template<int EPI>
__global__ __launch_bounds__(512, 2) void gemm8p(
    const u16* __restrict__ A, int lda,
    const u16* __restrict__ Bt,
    const float* __restrict__ bias,
    const float* __restrict__ R, int ldr,
    u16* __restrict__ Cb, float* __restrict__ Cf, int ldc,
    int K, int nbn)
{
    __shared__ __align__(16) u16 lds[65536];   // 128 KB
    const int tid = threadIdx.x, lane = tid & 63, wid = tid >> 6;
    const int wm = wid >> 2, wn = wid & 3;
    const int l15 = lane & 15, quad = lane >> 4;
    const char* ldsb = (const char*)lds;
    const int wmB = wm * 16384;                 // A half per wave-M
    const int wnB = (wn >> 1) * 16384;          // B half per wave-N
    const int wnR = (wn & 1) * 64;              // row base within B half
    const int qb = quad * 16;

    // bijective XCD swizzle (nwg % 8 == 0 for all our grids), bn fastest
    const int nwg = (int)gridDim.x;
    const int sw = ((int)blockIdx.x & 7) * (nwg >> 3) + ((int)blockIdx.x >> 3);
    const int bn = sw % nbn, bm = sw / nbn;
    const int rowA0 = bm * 256, rowB0 = bn * 256;

#define STG_A(t, h) stage_half(A + (size_t)(rowA0 + (h) * 128) * lda + (t) * 64, lda, \
                               lds + ((t) & 1) * 32768 + (h) * 8192, wid, lane)
#define STG_B(t, h) stage_half(Bt + (size_t)(rowB0 + (h) * 128) * K + (t) * 64, K, \
                               lds + ((t) & 1) * 32768 + 16384 + (h) * 8192, wid, lane)
#define LDA8(P, MQ, mi, ks) \
    (*(const bf16x8*)(ldsb + (P) * 65536 + wmB + \
        SWZ(((MQ) * 64 + (mi) * 16 + l15) * 128 + (ks) * 64 + qb)))
#define LDB8(P, nf, ks) \
    (*(const bf16x8*)(ldsb + (P) * 65536 + 32768 + wnB + \
        SWZ((wnR + (nf) * 16 + l15) * 128 + (ks) * 64 + qb)))
#define READ_A(P, MQ) \
    _Pragma("unroll") \
    for (int mi = 0; mi < 4; ++mi) { aF[mi*2] = LDA8(P, MQ, mi, 0); aF[mi*2+1] = LDA8(P, MQ, mi, 1); }
#define READ_B(P, NQ) \
    _Pragma("unroll") \
    for (int ni = 0; ni < 2; ++ni) { bF[NQ][ni*2] = LDB8(P, (NQ)*2+ni, 0); bF[NQ][ni*2+1] = LDB8(P, (NQ)*2+ni, 1); }
#define MFMA_Q(MQ, NQ) \
    __builtin_amdgcn_s_setprio(1); \
    _Pragma("unroll") \
    for (int mi = 0; mi < 4; ++mi) \
        _Pragma("unroll") \
        for (int ni = 0; ni < 2; ++ni) { \
            acc[(MQ)*4+mi][(NQ)*2+ni] = MFMA16(aF[mi*2],   bF[NQ][ni*2],   acc[(MQ)*4+mi][(NQ)*2+ni]); \
            acc[(MQ)*4+mi][(NQ)*2+ni] = MFMA16(aF[mi*2+1], bF[NQ][ni*2+1], acc[(MQ)*4+mi][(NQ)*2+ni]); \
        } \
    __builtin_amdgcn_s_setprio(0);

    floatx4 acc[8][4] = {};
    bf16x8 aF[8], bF[2][4];

    const int NI = K >> 7;   // two BK=64 tiles per iter

    // prologue: tile0 {B0,B1,A0,A1}->buf0, tile1 {B0,B1}->buf1 (12 vmem insts)
    STG_B(0, 0); STG_B(0, 1); STG_A(0, 0); STG_A(0, 1);
    STG_B(1, 0); STG_B(1, 1);
    WAITVM(4);        // tile0 fully landed; tile1 B halves may be in flight
    BARRIER();

    for (int i = 0; i < NI; ++i) {
        const int tE = 2 * i, tO = 2 * i + 1;
        const bool pre = (i + 1 < NI);

        // ---- P1: even (M0,N0) ; stage A0(odd)->buf1 (freed prev-P7) ----
        READ_A(0, 0); READ_B(0, 0);
        STG_A(tO, 0);
        BARRIER(); MFMA_Q(0, 0); BARRIER();

        // ---- P2: even (M0,N1) ; stage A1(odd)->buf1 ----
        READ_B(0, 1);
        STG_A(tO, 1);
        BARRIER(); MFMA_Q(0, 1); BARRIER();

        // ---- P3: even (M1,N1) ; stage B0(tE+2)->buf0 (B freed after P2) ----
        READ_A(0, 1);
        if (pre) STG_B(tE + 2, 0);
        BARRIER(); MFMA_Q(1, 1); BARRIER();

        // ---- P4: even (M1,N0) ; stage B1(tE+2) ; gate odd-tile data ----
        if (pre) { STG_B(tE + 2, 1); WAITVM(4); } else { WAITVM(0); }
        BARRIER(); MFMA_Q(1, 0); BARRIER();

        // ---- P5: odd (M0,N0) ; stage A0(tE+2)->buf0 (A freed after P3) ----
        READ_A(1, 0); READ_B(1, 0);
        if (pre) STG_A(tE + 2, 0);
        BARRIER(); MFMA_Q(0, 0); BARRIER();

        // ---- P6: odd (M0,N1) ; stage A1(tE+2)->buf0 ----
        READ_B(1, 1);
        if (pre) STG_A(tE + 2, 1);
        BARRIER(); MFMA_Q(0, 1); BARRIER();

        // ---- P7: odd (M1,N1) ; stage B0(tO+2)->buf1 (B freed after P6) ----
        READ_A(1, 1);
        if (pre) STG_B(tO + 2, 0);
        BARRIER(); MFMA_Q(1, 1); BARRIER();

        // ---- P8: odd (M1,N0) ; stage B1(tO+2) ; gate next even tile ----
        if (pre) STG_B(tO + 2, 1);
        WAITVM(4);     // leaves only P7/P8 stages in flight; tE+2 fully landed
        BARRIER(); MFMA_Q(1, 0); BARRIER();
    }

    // epilogue: C/D frag map col=lane&15, row=quad*4+r (verified m89/m91)
#pragma unroll
    for (int mq = 0; mq < 2; ++mq)
#pragma unroll
        for (int mi = 0; mi < 4; ++mi) {
            const int row = rowA0 + wm * 128 + mq * 64 + mi * 16 + quad * 4;
#pragma unroll
            for (int nf = 0; nf < 4; ++nf) {
                const int col = rowB0 + wn * 64 + nf * 16 + l15;
                const float bv = bias[col];
                const floatx4 v = acc[mq * 4 + mi][nf];
                if (EPI == 0) {
#pragma unroll
                    for (int r = 0; r < 4; ++r)
                        Cb[(size_t)(row + r) * ldc + col] = f2bf(v[r] + bv);
                } else {
#pragma unroll
                    for (int r = 0; r < 4; ++r)
                        Cf[(size_t)(row + r) * ldc + col] =
                            v[r] + bv + R[(size_t)(row + r) * ldr + col];
                }
            }
        }
}

// elementwise f32 -> bf16, 8 elems/thread
__global__ __launch_bounds__(256) void convert_f32_bf16(
    const float* __restrict__ src, u16* __restrict__ dst)
{
    const size_t i = ((size_t)blockIdx.x * 256 + threadIdx.x) * 8;
    float4 a = *(const float4*)(src + i);
    float4 b = *(const float4*)(src + i + 4);
    *(uint4*)(dst + i) = make_uint4(pk2(a.x, a.y), pk2(a.z, a.w),
                                    pk2(b.x, b.y), pk2(b.z, b.w));
}

#define AW 136  // padded LDS row width (floats)

// Per-position cross-head attention: one wave per (b,t); H=8, HD=128.
__global__ __launch_bounds__(256) void attn8(
    const u16* Q,
    const u16* __restrict__ KV,
    u16* O,
    int qstride, int kvstride)
{
    __shared__ __align__(16) float lds[4 * (3 * 8 * AW + 64)];
    const int wid = threadIdx.x >> 6, lane = threadIdx.x & 63;
    float* qs = lds + wid * (3 * 8 * AW + 64);
    float* ks = qs + 8 * AW;
    float* vs = ks + 8 * AW;
    float* ws = vs + 8 * AW;
    const size_t pos = (size_t)blockIdx.x * 4 + wid;
    const u16* qrow  = Q  + pos * qstride;
    const u16* kvrow = KV + pos * kvstride;

#pragma unroll
    for (int it = 0; it < 2; it++) {
        int vi = lane + 64 * it;
        int h = vi >> 4, c = (vi & 15) * 8;
        uint4 r = *(const uint4*)(qrow + vi * 8);
        float f0 = __uint_as_float(r.x << 16), f1 = __uint_as_float(r.x & 0xffff0000u);
        float f2 = __uint_as_float(r.y << 16), f3 = __uint_as_float(r.y & 0xffff0000u);
        float f4 = __uint_as_float(r.z << 16), f5 = __uint_as_float(r.z & 0xffff0000u);
        float f6 = __uint_as_float(r.w << 16), f7 = __uint_as_float(r.w & 0xffff0000u);
        float4* d = (float4*)&qs[h * AW + c];
        d[0] = make_float4(f0, f1, f2, f3);
        d[1] = make_float4(f4, f5, f6, f7);
    }
#pragma unroll
    for (int it = 0; it < 4; it++) {
        int vi = lane + 64 * it;
        int g = vi >> 5, c = (vi & 31) * 8;
        uint4 r = *(const uint4*)(kvrow + vi * 8);
        float f0 = __uint_as_float(r.x << 16), f1 = __uint_as_float(r.x & 0xffff0000u);
        float f2 = __uint_as_float(r.y << 16), f3 = __uint_as_float(r.y & 0xffff0000u);
        float f4 = __uint_as_float(r.z << 16), f5 = __uint_as_float(r.z & 0xffff0000u);
        float f6 = __uint_as_float(r.w << 16), f7 = __uint_as_float(r.w & 0xffff0000u);
        float* base = (c < 128) ? &ks[g * AW + c] : &vs[g * AW + (c - 128)];
        ((float4*)base)[0] = make_float4(f0, f1, f2, f3);
        ((float4*)base)[1] = make_float4(f4, f5, f6, f7);
    }
    __syncthreads();

    const int h = lane >> 3, g = lane & 7;
    float s = 0.f;
#pragma unroll 8
    for (int d = 0; d < 128; d += 4) {
        float4 qv = *(const float4*)&qs[h * AW + d];
        float4 kv = *(const float4*)&ks[g * AW + d];
        s += qv.x * kv.x + qv.y * kv.y + qv.z * kv.z + qv.w * kv.w;
    }
    s *= 0.08838834764831845f;
    float m = s;
    m = fmaxf(m, __shfl_xor(m, 1, 64));
    m = fmaxf(m, __shfl_xor(m, 2, 64));
    m = fmaxf(m, __shfl_xor(m, 4, 64));
    float p = __expf(s - m);
    float sum = p;
    sum += __shfl_xor(sum, 1, 64);
    sum += __shfl_xor(sum, 2, 64);
    sum += __shfl_xor(sum, 4, 64);
    ws[lane] = p / sum;
    __syncthreads();

    const int db = lane & 7;
    float o[16];
#pragma unroll
    for (int j = 0; j < 16; j++) o[j] = 0.f;
#pragma unroll
    for (int g2 = 0; g2 < 8; g2++) {
        float wv = ws[h * 8 + g2];
        const float* vr = &vs[g2 * AW + db * 16];
#pragma unroll
        for (int j = 0; j < 16; j++) o[j] += wv * vr[j];
    }
    u16* orow = O + pos * qstride + h * 128 + db * 16;
    u32 pk[8];
#pragma unroll
    for (int j = 0; j < 8; j++)
        pk[j] = (u32)f2bf(o[2 * j]) | ((u32)f2bf(o[2 * j + 1]) << 16);
    ((uint4*)orow)[0] = make_uint4(pk[0], pk[1], pk[2], pk[3]);
    ((uint4*)orow)[1] = make_uint4(pk[4], pk[5], pk[6], pk[7]);
}

// src f32 (K,N) row-major -> dst bf16 (N,K) row-major
__global__ __launch_bounds__(256) void transpose_f32_bf16(
    const float* __restrict__ src, u16* __restrict__ dst, int K, int N)
{
    __shared__ float tile[32][33];
    const int tx = threadIdx.x & 31, ty = threadIdx.x >> 5;
    const int c0 = blockIdx.x * 32, r0 = blockIdx.y * 32;
#pragma unroll
    for (int i = 0; i < 4; i++)
        tile[ty + i * 8][tx] = src[(size_t)(r0 + ty + i * 8) * N + c0 + tx];
    __syncthreads();
#pragma unroll
    for (int i = 0; i < 4; i++)
        dst[(size_t)(c0 + ty + i * 8) * K + r0 + tx] = f2bf(tile[tx][ty + i * 8]);
}

extern "C" void kernel_launch(void* const* d_in, const int* in_sizes, int n_in,
                              void* d_out, int out_size, void* d_ws, size_t ws_size,
                              hipStream_t stream) {
    const float* liquid = (const float*)d_in[0];
    const float* mamba  = (const float*)d_in[1];
    const float* Wlq  = (const float*)d_in[2];
    const float* blq  = (const float*)d_in[3];
    const float* Wmkv = (const float*)d_in[4];
    const float* bmkv = (const float*)d_in[5];
    const float* Wmq  = (const float*)d_in[6];
    const float* bmq  = (const float*)d_in[7];
    const float* Wlkv = (const float*)d_in[8];
    const float* blkv = (const float*)d_in[9];
    const float* Wlo  = (const float*)d_in[10];
    const float* blo  = (const float*)d_in[11];
    const float* Wmo  = (const float*)d_in[12];
    const float* bmo  = (const float*)d_in[13];
    float* out = (float*)d_out;   // [enhanced_liquid | enhanced_mamba], each 32768x1024 fp32

    // workspace carve (bf16)
    u16* p = (u16*)d_ws;
    u16* WtLq  = p; p += (size_t)1024 * 1024;
    u16* WtLkv = p; p += (size_t)2048 * 1024;
    u16* WtMq  = p; p += (size_t)1024 * 1024;
    u16* WtMkv = p; p += (size_t)2048 * 1024;
    u16* WtLo  = p; p += (size_t)1024 * 1024;
    u16* WtMo  = p; p += (size_t)1024 * 1024;
    u16* Q  = p; p += (size_t)32768 * 1024;
    u16* KV = p;

    // bf16 activations in second half of d_out (only written by the final GEMM,
    // strictly after their last read — stream-ordered, no race)
    u16* Lb = (u16*)(out + (size_t)32768 * 1024);
    u16* Mb = Lb + (size_t)32768 * 1024;

    transpose_f32_bf16<<<dim3(32, 32), 256, 0, stream>>>(Wlq,  WtLq,  1024, 1024);
    transpose_f32_bf16<<<dim3(64, 32), 256, 0, stream>>>(Wlkv, WtLkv, 1024, 2048);
    transpose_f32_bf16<<<dim3(32, 32), 256, 0, stream>>>(Wmq,  WtMq,  1024, 1024);
    transpose_f32_bf16<<<dim3(64, 32), 256, 0, stream>>>(Wmkv, WtMkv, 1024, 2048);
    transpose_f32_bf16<<<dim3(32, 32), 256, 0, stream>>>(Wlo,  WtLo,  1024, 1024);
    transpose_f32_bf16<<<dim3(32, 32), 256, 0, stream>>>(Wmo,  WtMo,  1024, 1024);

    convert_f32_bf16<<<16384, 256, 0, stream>>>(liquid, Lb);
    convert_f32_bf16<<<16384, 256, 0, stream>>>(mamba,  Mb);

    // ---- phase L: enhanced_liquid ----
    gemm8p<0><<<512,  512, 0, stream>>>(Lb, 1024, WtLq,  blq,  nullptr, 0,
                                        Q,  nullptr, 1024, 1024, 4);
    gemm8p<0><<<1024, 512, 0, stream>>>(Mb, 1024, WtMkv, bmkv, nullptr, 0,
                                        KV, nullptr, 2048, 1024, 8);
    attn8<<<8192, 256, 0, stream>>>(Q, KV, Q, 1024, 2048);
    gemm8p<1><<<512,  512, 0, stream>>>(Q, 1024, WtLo, blo, liquid, 1024,
                                        nullptr, out, 1024, 1024, 4);

    // ---- phase M: enhanced_mamba ----
    gemm8p<0><<<512,  512, 0, stream>>>(Mb, 1024, WtMq,  bmq,  nullptr, 0,
                                        Q,  nullptr, 1024, 1024, 4);
    gemm8p<0><<<1024, 512, 0, stream>>>(Lb, 1024, WtLkv, blkv, nullptr, 0,
                                        KV, nullptr, 2048, 1024, 8);
    attn8<<<8192, 256, 0, stream>>>(Q, KV, Q, 1024, 2048);
    gemm8p<1><<<512,  512, 0, stream>>>(Q, 1024, WtMo, bmo, mamba, 1024,
                                        nullptr, out + (size_t)32768 * 1024, 1024, 1024, 4);
}

// Round 3
// 2096.742 us; speedup vs baseline: 1.0118x; 1.0118x over previous
//
#include <hip/hip_runtime.h>

typedef unsigned short u16;
typedef unsigned int u32;

typedef __attribute__((ext_vector_type(4))) float floatx4;
typedef __attribute__((ext_vector_type(8))) __bf16 bf16x8;

typedef __attribute__((address_space(3))) u32 lds_u32_t;
typedef __attribute__((address_space(1))) u32 glb_u32_t;

__device__ __forceinline__ void gld_lds16(const u16* g, u16* l) {
    __builtin_amdgcn_global_load_lds((glb_u32_t*)g, (lds_u32_t*)l, 16, 0, 0);
}

__device__ __forceinline__ u16 f2bf(float f) {
    u32 u = __float_as_uint(f);
    u += 0x7fffu + ((u >> 16) & 1u);
    return (u16)(u >> 16);
}
// pack two fp32 -> two bf16 (RNE) in one u32
__device__ __forceinline__ u32 pk2(float a, float b) {
    u32 x = __float_as_uint(a), y = __float_as_uint(b);
    x += 0x7fffu + ((x >> 16) & 1u);
    y += 0x7fffu + ((y >> 16) & 1u);
    return (x >> 16) | (y & 0xffff0000u);
}

// raw barrier: no vmcnt drain (the whole point of the counted pipeline);
// "memory" clobber pins all compiler-visible memory ops to their phase.
#define BARRIER() asm volatile("s_barrier" ::: "memory")
#define WAITVM(N) asm volatile("s_waitcnt vmcnt(" #N ")" ::: "memory")
// XOR-swizzle (G4): inject row bits 0-2 (byte bits 7-9 of a 128B-row tile)
// into the 16B-slot index (byte bits 4-6). Involution within 1024B (8 rows).
// Spreads a quad's 16 rows across all 8 slots -> 2 lanes/slot (free, m136).
#define SWZ(d) ((d) ^ ((((d) >> 7) & 7) << 4))
#define MFMA16(a, b, c) __builtin_amdgcn_mfma_f32_16x16x32_bf16(a, b, c, 0, 0, 0)

// Stage one 16KB half-tile (128 rows x 64 cols bf16) g->LDS via global_load_lds.
// LDS dest is linear (wave-uniform base + lane*16); the swizzle permutation is
// applied by pre-swizzling the per-lane GLOBAL source chunk (same involution at
// 16B-chunk granularity: chunk bits 0-2 ^= chunk bits 3-5 = row&7).
__device__ __forceinline__ void stage_half(const u16* __restrict__ g, int ld,
                                           u16* halfdst, int wid, int lane)
{
#pragma unroll
    for (int j = 0; j < 2; ++j) {
        const int clin = wid * 128 + j * 64 + lane;   // 16B chunk idx in half
        const int csrc = clin ^ ((clin >> 3) & 7);    // chunk-level SWZ
        gld_lds16(g + (size_t)(csrc >> 3) * ld + (csrc & 7) * 8,
                  halfdst + clin * 8);
    }
}

// ===================== 256x256 8-phase GEMM (m201 template) =====================
// C = A[M,K](bf16) @ Bt[N,K]^T(bf16) + bias;  EPI==0: C bf16;  EPI==1: C f32 += R
// 512 thr = 8 waves (2M x 4N); per-wave out 128x64; BK=64, 2 K-tiles/iter;
// LDS 128KB = 2 bufs x (A 32KB | B 32KB), halves of 16KB each.
template<int EPI>
__global__ __launch_bounds__(512, 2) void gemm8p(
    const u16* __restrict__ A, int lda,
    const u16* __restrict__ Bt,
    const float* __restrict__ bias,
    const float* __restrict__ R, int ldr,
    u16* __restrict__ Cb, float* __restrict__ Cf, int ldc,
    int K, int nbn)
{
    __shared__ __align__(16) u16 lds[65536];   // 128 KB
    const int tid = threadIdx.x, lane = tid & 63, wid = tid >> 6;
    const int wm = wid >> 2, wn = wid & 3;
    const int l15 = lane & 15, quad = lane >> 4;
    const char* ldsb = (const char*)lds;
    const int wmB = wm * 16384;                 // A half per wave-M
    const int wnB = (wn >> 1) * 16384;          // B half per wave-N
    const int wnR = (wn & 1) * 64;              // row base within B half
    const int qb = quad * 16;

    // bijective XCD swizzle (nwg % 8 == 0 for all our grids), bn fastest
    const int nwg = (int)gridDim.x;
    const int sw = ((int)blockIdx.x & 7) * (nwg >> 3) + ((int)blockIdx.x >> 3);
    const int bn = sw % nbn, bm = sw / nbn;
    const int rowA0 = bm * 256, rowB0 = bn * 256;

#define STG_A(t, h) stage_half(A + (size_t)(rowA0 + (h) * 128) * lda + (t) * 64, lda, \
                               lds + ((t) & 1) * 32768 + (h) * 8192, wid, lane)
#define STG_B(t, h) stage_half(Bt + (size_t)(rowB0 + (h) * 128) * K + (t) * 64, K, \
                               lds + ((t) & 1) * 32768 + 16384 + (h) * 8192, wid, lane)
#define LDA8(P, MQ, mi, ks) \
    (*(const bf16x8*)(ldsb + (P) * 65536 + wmB + \
        SWZ(((MQ) * 64 + (mi) * 16 + l15) * 128 + (ks) * 64 + qb)))
#define LDB8(P, nf, ks) \
    (*(const bf16x8*)(ldsb + (P) * 65536 + 32768 + wnB + \
        SWZ((wnR + (nf) * 16 + l15) * 128 + (ks) * 64 + qb)))
#define READ_A(P, MQ) \
    _Pragma("unroll") \
    for (int mi = 0; mi < 4; ++mi) { aF[mi*2] = LDA8(P, MQ, mi, 0); aF[mi*2+1] = LDA8(P, MQ, mi, 1); }
#define READ_B(P, NQ) \
    _Pragma("unroll") \
    for (int ni = 0; ni < 2; ++ni) { bF[NQ][ni*2] = LDB8(P, (NQ)*2+ni, 0); bF[NQ][ni*2+1] = LDB8(P, (NQ)*2+ni, 1); }
#define MFMA_Q(MQ, NQ) \
    __builtin_amdgcn_s_setprio(1); \
    _Pragma("unroll") \
    for (int mi = 0; mi < 4; ++mi) \
        _Pragma("unroll") \
        for (int ni = 0; ni < 2; ++ni) { \
            acc[(MQ)*4+mi][(NQ)*2+ni] = MFMA16(aF[mi*2],   bF[NQ][ni*2],   acc[(MQ)*4+mi][(NQ)*2+ni]); \
            acc[(MQ)*4+mi][(NQ)*2+ni] = MFMA16(aF[mi*2+1], bF[NQ][ni*2+1], acc[(MQ)*4+mi][(NQ)*2+ni]); \
        } \
    __builtin_amdgcn_s_setprio(0);

    floatx4 acc[8][4] = {};
    bf16x8 aF[8], bF[2][4];

    const int NI = K >> 7;   // two BK=64 tiles per iter

    // prologue: tile0 {B0,B1,A0,A1}->buf0, tile1 {B0,B1}->buf1 (12 vmem insts)
    STG_B(0, 0); STG_B(0, 1); STG_A(0, 0); STG_A(0, 1);
    STG_B(1, 0); STG_B(1, 1);
    WAITVM(4);        // tile0 fully landed; tile1 B halves may be in flight
    BARRIER();

    for (int i = 0; i < NI; ++i) {
        const int tE = 2 * i, tO = 2 * i + 1;
        const bool pre = (i + 1 < NI);

        // ---- P1: even (M0,N0) ; stage A0(odd)->buf1 (freed prev-P7) ----
        READ_A(0, 0); READ_B(0, 0);
        STG_A(tO, 0);
        BARRIER(); MFMA_Q(0, 0); BARRIER();

        // ---- P2: even (M0,N1) ; stage A1(odd)->buf1 ----
        READ_B(0, 1);
        STG_A(tO, 1);
        BARRIER(); MFMA_Q(0, 1); BARRIER();

        // ---- P3: even (M1,N1) ; stage B0(tE+2)->buf0 (B freed after P2) ----
        READ_A(0, 1);
        if (pre) STG_B(tE + 2, 0);
        BARRIER(); MFMA_Q(1, 1); BARRIER();

        // ---- P4: even (M1,N0) ; stage B1(tE+2) ; gate odd-tile data ----
        if (pre) { STG_B(tE + 2, 1); WAITVM(4); } else { WAITVM(0); }
        BARRIER(); MFMA_Q(1, 0); BARRIER();

        // ---- P5: odd (M0,N0) ; stage A0(tE+2)->buf0 (A freed after P3) ----
        READ_A(1, 0); READ_B(1, 0);
        if (pre) STG_A(tE + 2, 0);
        BARRIER(); MFMA_Q(0, 0); BARRIER();

        // ---- P6: odd (M0,N1) ; stage A1(tE+2)->buf0 ----
        READ_B(1, 1);
        if (pre) STG_A(tE + 2, 1);
        BARRIER(); MFMA_Q(0, 1); BARRIER();

        // ---- P7: odd (M1,N1) ; stage B0(tO+2)->buf1 (B freed after P6) ----
        READ_A(1, 1);
        if (pre) STG_B(tO + 2, 0);
        BARRIER(); MFMA_Q(1, 1); BARRIER();

        // ---- P8: odd (M1,N0) ; stage B1(tO+2) ; gate next even tile ----
        if (pre) STG_B(tO + 2, 1);
        WAITVM(4);     // leaves only P7/P8 stages in flight; tE+2 fully landed
        BARRIER(); MFMA_Q(1, 0); BARRIER();
    }

    // epilogue: C/D frag map col=lane&15, row=quad*4+r (verified m89/m91)
#pragma unroll
    for (int mq = 0; mq < 2; ++mq)
#pragma unroll
        for (int mi = 0; mi < 4; ++mi) {
            const int row = rowA0 + wm * 128 + mq * 64 + mi * 16 + quad * 4;
#pragma unroll
            for (int nf = 0; nf < 4; ++nf) {
                const int col = rowB0 + wn * 64 + nf * 16 + l15;
                const float bv = bias[col];
                const floatx4 v = acc[mq * 4 + mi][nf];
                if (EPI == 0) {
#pragma unroll
                    for (int r = 0; r < 4; ++r)
                        Cb[(size_t)(row + r) * ldc + col] = f2bf(v[r] + bv);
                } else {
#pragma unroll
                    for (int r = 0; r < 4; ++r)
                        Cf[(size_t)(row + r) * ldc + col] =
                            v[r] + bv + R[(size_t)(row + r) * ldr + col];
                }
            }
        }
}

// elementwise f32 -> bf16, 8 elems/thread
__global__ __launch_bounds__(256) void convert_f32_bf16(
    const float* __restrict__ src, u16* __restrict__ dst)
{
    const size_t i = ((size_t)blockIdx.x * 256 + threadIdx.x) * 8;
    float4 a = *(const float4*)(src + i);
    float4 b = *(const float4*)(src + i + 4);
    *(uint4*)(dst + i) = make_uint4(pk2(a.x, a.y), pk2(a.z, a.w),
                                    pk2(b.x, b.y), pk2(b.z, b.w));
}

#define AW 136  // padded LDS row width (floats)

// Per-position cross-head attention: one wave per (b,t); H=8, HD=128.
__global__ __launch_bounds__(256) void attn8(
    const u16* Q,
    const u16* __restrict__ KV,
    u16* O,
    int qstride, int kvstride)
{
    __shared__ __align__(16) float lds[4 * (3 * 8 * AW + 64)];
    const int wid = threadIdx.x >> 6, lane = threadIdx.x & 63;
    float* qs = lds + wid * (3 * 8 * AW + 64);
    float* ks = qs + 8 * AW;
    float* vs = ks + 8 * AW;
    float* ws = vs + 8 * AW;
    const size_t pos = (size_t)blockIdx.x * 4 + wid;
    const u16* qrow  = Q  + pos * qstride;
    const u16* kvrow = KV + pos * kvstride;

#pragma unroll
    for (int it = 0; it < 2; it++) {
        int vi = lane + 64 * it;
        int h = vi >> 4, c = (vi & 15) * 8;
        uint4 r = *(const uint4*)(qrow + vi * 8);
        float f0 = __uint_as_float(r.x << 16), f1 = __uint_as_float(r.x & 0xffff0000u);
        float f2 = __uint_as_float(r.y << 16), f3 = __uint_as_float(r.y & 0xffff0000u);
        float f4 = __uint_as_float(r.z << 16), f5 = __uint_as_float(r.z & 0xffff0000u);
        float f6 = __uint_as_float(r.w << 16), f7 = __uint_as_float(r.w & 0xffff0000u);
        float4* d = (float4*)&qs[h * AW + c];
        d[0] = make_float4(f0, f1, f2, f3);
        d[1] = make_float4(f4, f5, f6, f7);
    }
#pragma unroll
    for (int it = 0; it < 4; it++) {
        int vi = lane + 64 * it;
        int g = vi >> 5, c = (vi & 31) * 8;
        uint4 r = *(const uint4*)(kvrow + vi * 8);
        float f0 = __uint_as_float(r.x << 16), f1 = __uint_as_float(r.x & 0xffff0000u);
        float f2 = __uint_as_float(r.y << 16), f3 = __uint_as_float(r.y & 0xffff0000u);
        float f4 = __uint_as_float(r.z << 16), f5 = __uint_as_float(r.z & 0xffff0000u);
        float f6 = __uint_as_float(r.w << 16), f7 = __uint_as_float(r.w & 0xffff0000u);
        float* base = (c < 128) ? &ks[g * AW + c] : &vs[g * AW + (c - 128)];
        ((float4*)base)[0] = make_float4(f0, f1, f2, f3);
        ((float4*)base)[1] = make_float4(f4, f5, f6, f7);
    }
    __syncthreads();

    const int h = lane >> 3, g = lane & 7;
    float s = 0.f;
#pragma unroll 8
    for (int d = 0; d < 128; d += 4) {
        float4 qv = *(const float4*)&qs[h * AW + d];
        float4 kv = *(const float4*)&ks[g * AW + d];
        s += qv.x * kv.x + qv.y * kv.y + qv.z * kv.z + qv.w * kv.w;
    }
    s *= 0.08838834764831845f;
    float m = s;
    m = fmaxf(m, __shfl_xor(m, 1, 64));
    m = fmaxf(m, __shfl_xor(m, 2, 64));
    m = fmaxf(m, __shfl_xor(m, 4, 64));
    float p = __expf(s - m);
    float sum = p;
    sum += __shfl_xor(sum, 1, 64);
    sum += __shfl_xor(sum, 2, 64);
    sum += __shfl_xor(sum, 4, 64);
    ws[lane] = p / sum;
    __syncthreads();

    const int db = lane & 7;
    float o[16];
#pragma unroll
    for (int j = 0; j < 16; j++) o[j] = 0.f;
#pragma unroll
    for (int g2 = 0; g2 < 8; g2++) {
        float wv = ws[h * 8 + g2];
        const float* vr = &vs[g2 * AW + db * 16];
#pragma unroll
        for (int j = 0; j < 16; j++) o[j] += wv * vr[j];
    }
    u16* orow = O + pos * qstride + h * 128 + db * 16;
    u32 pk[8];
#pragma unroll
    for (int j = 0; j < 8; j++)
        pk[j] = (u32)f2bf(o[2 * j]) | ((u32)f2bf(o[2 * j + 1]) << 16);
    ((uint4*)orow)[0] = make_uint4(pk[0], pk[1], pk[2], pk[3]);
    ((uint4*)orow)[1] = make_uint4(pk[4], pk[5], pk[6], pk[7]);
}

// src f32 (K,N) row-major -> dst bf16 (N,K) row-major
__global__ __launch_bounds__(256) void transpose_f32_bf16(
    const float* __restrict__ src, u16* __restrict__ dst, int K, int N)
{
    __shared__ float tile[32][33];
    const int tx = threadIdx.x & 31, ty = threadIdx.x >> 5;
    const int c0 = blockIdx.x * 32, r0 = blockIdx.y * 32;
#pragma unroll
    for (int i = 0; i < 4; i++)
        tile[ty + i * 8][tx] = src[(size_t)(r0 + ty + i * 8) * N + c0 + tx];
    __syncthreads();
#pragma unroll
    for (int i = 0; i < 4; i++)
        dst[(size_t)(c0 + ty + i * 8) * K + r0 + tx] = f2bf(tile[tx][ty + i * 8]);
}

extern "C" void kernel_launch(void* const* d_in, const int* in_sizes, int n_in,
                              void* d_out, int out_size, void* d_ws, size_t ws_size,
                              hipStream_t stream) {
    const float* liquid = (const float*)d_in[0];
    const float* mamba  = (const float*)d_in[1];
    const float* Wlq  = (const float*)d_in[2];
    const float* blq  = (const float*)d_in[3];
    const float* Wmkv = (const float*)d_in[4];
    const float* bmkv = (const float*)d_in[5];
    const float* Wmq  = (const float*)d_in[6];
    const float* bmq  = (const float*)d_in[7];
    const float* Wlkv = (const float*)d_in[8];
    const float* blkv = (const float*)d_in[9];
    const float* Wlo  = (const float*)d_in[10];
    const float* blo  = (const float*)d_in[11];
    const float* Wmo  = (const float*)d_in[12];
    const float* bmo  = (const float*)d_in[13];
    float* out = (float*)d_out;   // [enhanced_liquid | enhanced_mamba], each 32768x1024 fp32

    // workspace carve (bf16)
    u16* p = (u16*)d_ws;
    u16* WtLq  = p; p += (size_t)1024 * 1024;
    u16* WtLkv = p; p += (size_t)2048 * 1024;
    u16* WtMq  = p; p += (size_t)1024 * 1024;
    u16* WtMkv = p; p += (size_t)2048 * 1024;
    u16* WtLo  = p; p += (size_t)1024 * 1024;
    u16* WtMo  = p; p += (size_t)1024 * 1024;
    u16* Q  = p; p += (size_t)32768 * 1024;
    u16* KV = p;

    // bf16 activations in second half of d_out (only written by the final GEMM,
    // strictly after their last read — stream-ordered, no race)
    u16* Lb = (u16*)(out + (size_t)32768 * 1024);
    u16* Mb = Lb + (size_t)32768 * 1024;

    transpose_f32_bf16<<<dim3(32, 32), 256, 0, stream>>>(Wlq,  WtLq,  1024, 1024);
    transpose_f32_bf16<<<dim3(64, 32), 256, 0, stream>>>(Wlkv, WtLkv, 1024, 2048);
    transpose_f32_bf16<<<dim3(32, 32), 256, 0, stream>>>(Wmq,  WtMq,  1024, 1024);
    transpose_f32_bf16<<<dim3(64, 32), 256, 0, stream>>>(Wmkv, WtMkv, 1024, 2048);
    transpose_f32_bf16<<<dim3(32, 32), 256, 0, stream>>>(Wlo,  WtLo,  1024, 1024);
    transpose_f32_bf16<<<dim3(32, 32), 256, 0, stream>>>(Wmo,  WtMo,  1024, 1024);

    convert_f32_bf16<<<16384, 256, 0, stream>>>(liquid, Lb);
    convert_f32_bf16<<<16384, 256, 0, stream>>>(mamba,  Mb);

    // ---- phase L: enhanced_liquid ----
    gemm8p<0><<<512,  512, 0, stream>>>(Lb, 1024, WtLq,  blq,  nullptr, 0,
                                        Q,  nullptr, 1024, 1024, 4);
    gemm8p<0><<<1024, 512, 0, stream>>>(Mb, 1024, WtMkv, bmkv, nullptr, 0,
                                        KV, nullptr, 2048, 1024, 8);
    attn8<<<8192, 256, 0, stream>>>(Q, KV, Q, 1024, 2048);
    gemm8p<1><<<512,  512, 0, stream>>>(Q, 1024, WtLo, blo, liquid, 1024,
                                        nullptr, out, 1024, 1024, 4);

    // ---- phase M: enhanced_mamba ----
    gemm8p<0><<<512,  512, 0, stream>>>(Mb, 1024, WtMq,  bmq,  nullptr, 0,
                                        Q,  nullptr, 1024, 1024, 4);
    gemm8p<0><<<1024, 512, 0, stream>>>(Lb, 1024, WtLkv, blkv, nullptr, 0,
                                        KV, nullptr, 2048, 1024, 8);
    attn8<<<8192, 256, 0, stream>>>(Q, KV, Q, 1024, 2048);
    gemm8p<1><<<512,  512, 0, stream>>>(Q, 1024, WtMo, bmo, mamba, 1024,
                                        nullptr, out + (size_t)32768 * 1024, 1024, 1024, 4);
}

// Round 4
// 1356.799 us; speedup vs baseline: 1.5635x; 1.5454x over previous
//
#include <hip/hip_runtime.h>

typedef unsigned short u16;
typedef unsigned int u32;

typedef __attribute__((ext_vector_type(4))) float floatx4;
typedef __attribute__((ext_vector_type(8))) __bf16 bf16x8;

typedef __attribute__((address_space(3))) u32 lds_u32_t;
typedef __attribute__((address_space(1))) u32 glb_u32_t;

__device__ __forceinline__ void gld_lds16(const u16* g, u16* l) {
    __builtin_amdgcn_global_load_lds((glb_u32_t*)g, (lds_u32_t*)l, 16, 0, 0);
}

__device__ __forceinline__ u16 f2bf(float f) {
    u32 u = __float_as_uint(f);
    u += 0x7fffu + ((u >> 16) & 1u);
    return (u16)(u >> 16);
}
// pack two fp32 -> two bf16 (RNE) in one u32
__device__ __forceinline__ u32 pk2(float a, float b) {
    u32 x = __float_as_uint(a), y = __float_as_uint(b);
    x += 0x7fffu + ((x >> 16) & 1u);
    y += 0x7fffu + ((y >> 16) & 1u);
    return (x >> 16) | (y & 0xffff0000u);
}

// XOR-swizzle (verified R3: SQ_LDS_BANK_CONFLICT == 0, correctness passed):
// for 128B-row LDS tiles, inject row bits 0-2 (byte bits 7-9) into the 16B-slot
// index (byte bits 4-6). Involution within each 8-row stripe.
#define SWZ(d) ((d) ^ ((((d) >> 7) & 7) << 4))

#define BM 128
#define BN 128
#define BK 64   // 128B LDS rows; halves barrier-drain count vs BK=32

// elementwise f32 -> bf16, 8 elems/thread (count must be multiple of 2048*8)
__global__ __launch_bounds__(256) void convert_f32_bf16(
    const float* __restrict__ src, u16* __restrict__ dst)
{
    const size_t i = ((size_t)blockIdx.x * 256 + threadIdx.x) * 8;
    float4 a = *(const float4*)(src + i);
    float4 b = *(const float4*)(src + i + 4);
    *(uint4*)(dst + i) = make_uint4(pk2(a.x, a.y), pk2(a.z, a.w),
                                    pk2(b.x, b.y), pk2(b.z, b.w));
}

// C_bf16[M,N] = A_bf16[M,K] @ Bt_bf16[N,K]^T + bias_f32[N]
// m97 structure, BK=64, swizzled LDS (stage-source + read, same involution).
__global__ __launch_bounds__(256, 2) void gemm_a16_c16(
    const u16* __restrict__ A, int lda,
    const u16* __restrict__ Bt,
    const float* __restrict__ bias,
    u16* __restrict__ C, int ldc,
    int K)
{
    __shared__ __align__(16) u16 sA[BM * BK];   // 16 KB
    __shared__ __align__(16) u16 sB[BN * BK];   // 16 KB
    const int tid  = threadIdx.x;
    const int bm   = blockIdx.x, bn = blockIdx.y;
    const int lane = tid & 63,  wave = tid >> 6;
    const int wm   = wave >> 1, wn   = wave & 1;
    const int l15  = lane & 15, quad = lane >> 4;
    const char* sAb = (const char*)sA;
    const char* sBb = (const char*)sB;

    floatx4 acc[4][4] = {};

    for (int k0 = 0; k0 < K; k0 += BK) {
        __syncthreads();
        // stage 128x64 A and B tiles; LDS dest linear (chunk clin), global
        // source pre-swizzled by the same involution at 16B-chunk granularity
#pragma unroll
        for (int j = 0; j < 4; ++j) {
            const int clin = tid + j * 256;               // 16B chunk 0..1023
            const int csrc = clin ^ ((clin >> 3) & 7);    // chunk-level SWZ
            const int r = csrc >> 3, c = (csrc & 7) * 8;
            gld_lds16(A  + (size_t)(bm * BM + r) * lda + k0 + c, &sA[clin * 8]);
            gld_lds16(Bt + (size_t)(bn * BN + r) * K   + k0 + c, &sB[clin * 8]);
        }
        __syncthreads();

#pragma unroll
        for (int ks = 0; ks < 2; ++ks) {
            bf16x8 af[4], bfr[4];
#pragma unroll
            for (int mi = 0; mi < 4; mi++)
                af[mi] = *(const bf16x8*)(sAb +
                    SWZ((wm * 64 + mi * 16 + l15) * 128 + ks * 64 + quad * 16));
#pragma unroll
            for (int ni = 0; ni < 4; ni++)
                bfr[ni] = *(const bf16x8*)(sBb +
                    SWZ((wn * 64 + ni * 16 + l15) * 128 + ks * 64 + quad * 16));
#pragma unroll
            for (int mi = 0; mi < 4; mi++)
#pragma unroll
                for (int ni = 0; ni < 4; ni++)
                    acc[mi][ni] = __builtin_amdgcn_mfma_f32_16x16x32_bf16(
                        af[mi], bfr[ni], acc[mi][ni], 0, 0, 0);
        }
    }

    const int row0 = bm * BM + wm * 64 + quad * 4;
    const int col0 = bn * BN + wn * 64 + l15;
#pragma unroll
    for (int mi = 0; mi < 4; mi++) {
#pragma unroll
        for (int ni = 0; ni < 4; ni++) {
            const int col = col0 + ni * 16;
            const float bv = bias[col];
#pragma unroll
            for (int r = 0; r < 4; r++) {
                const int row = row0 + mi * 16 + r;
                C[(size_t)row * ldc + col] = f2bf(acc[mi][ni][r] + bv);
            }
        }
    }
}

// C_f32[M,N] = A_bf16[M,K] @ Bt_bf16[N,K]^T + bias_f32[N] + R_f32[M,N]
__global__ __launch_bounds__(256, 2) void gemm_a16_c32(
    const u16* __restrict__ A, int lda,
    const u16* __restrict__ Bt,
    const float* __restrict__ bias,
    const float* __restrict__ R, int ldr,
    float* __restrict__ C, int ldc,
    int K)
{
    __shared__ __align__(16) u16 sA[BM * BK];
    __shared__ __align__(16) u16 sB[BN * BK];
    const int tid  = threadIdx.x;
    const int bm   = blockIdx.x, bn = blockIdx.y;
    const int lane = tid & 63,  wave = tid >> 6;
    const int wm   = wave >> 1, wn   = wave & 1;
    const int l15  = lane & 15, quad = lane >> 4;
    const char* sAb = (const char*)sA;
    const char* sBb = (const char*)sB;

    floatx4 acc[4][4] = {};

    for (int k0 = 0; k0 < K; k0 += BK) {
        __syncthreads();
#pragma unroll
        for (int j = 0; j < 4; ++j) {
            const int clin = tid + j * 256;
            const int csrc = clin ^ ((clin >> 3) & 7);
            const int r = csrc >> 3, c = (csrc & 7) * 8;
            gld_lds16(A  + (size_t)(bm * BM + r) * lda + k0 + c, &sA[clin * 8]);
            gld_lds16(Bt + (size_t)(bn * BN + r) * K   + k0 + c, &sB[clin * 8]);
        }
        __syncthreads();

#pragma unroll
        for (int ks = 0; ks < 2; ++ks) {
            bf16x8 af[4], bfr[4];
#pragma unroll
            for (int mi = 0; mi < 4; mi++)
                af[mi] = *(const bf16x8*)(sAb +
                    SWZ((wm * 64 + mi * 16 + l15) * 128 + ks * 64 + quad * 16));
#pragma unroll
            for (int ni = 0; ni < 4; ni++)
                bfr[ni] = *(const bf16x8*)(sBb +
                    SWZ((wn * 64 + ni * 16 + l15) * 128 + ks * 64 + quad * 16));
#pragma unroll
            for (int mi = 0; mi < 4; mi++)
#pragma unroll
                for (int ni = 0; ni < 4; ni++)
                    acc[mi][ni] = __builtin_amdgcn_mfma_f32_16x16x32_bf16(
                        af[mi], bfr[ni], acc[mi][ni], 0, 0, 0);
        }
    }

    const int row0 = bm * BM + wm * 64 + quad * 4;
    const int col0 = bn * BN + wn * 64 + l15;
#pragma unroll
    for (int mi = 0; mi < 4; mi++) {
#pragma unroll
        for (int ni = 0; ni < 4; ni++) {
            const int col = col0 + ni * 16;
            const float bv = bias[col];
#pragma unroll
            for (int r = 0; r < 4; r++) {
                const int row = row0 + mi * 16 + r;
                C[(size_t)row * ldc + col] =
                    acc[mi][ni][r] + bv + R[(size_t)row * ldr + col];
            }
        }
    }
}

#define AW 136  // padded LDS row width (floats)

// Per-position cross-head attention: one wave per (b,t); H=8, HD=128.
// Q (bf16, qstride), KV (bf16, kvstride; per head g: [k(128)|v(128)]).
// Writes O in-place over Q (same-wave read-before-write only).
__global__ __launch_bounds__(256) void attn8(
    const u16* Q,
    const u16* __restrict__ KV,
    u16* O,
    int qstride, int kvstride)
{
    __shared__ __align__(16) float lds[4 * (3 * 8 * AW + 64)];
    const int wid = threadIdx.x >> 6, lane = threadIdx.x & 63;
    float* qs = lds + wid * (3 * 8 * AW + 64);
    float* ks = qs + 8 * AW;
    float* vs = ks + 8 * AW;
    float* ws = vs + 8 * AW;
    const size_t pos = (size_t)blockIdx.x * 4 + wid;
    const u16* qrow  = Q  + pos * qstride;
    const u16* kvrow = KV + pos * kvstride;

#pragma unroll
    for (int it = 0; it < 2; it++) {
        int vi = lane + 64 * it;          // 0..127 (8 bf16 each)
        int h = vi >> 4, c = (vi & 15) * 8;
        uint4 r = *(const uint4*)(qrow + vi * 8);
        float f0 = __uint_as_float(r.x << 16), f1 = __uint_as_float(r.x & 0xffff0000u);
        float f2 = __uint_as_float(r.y << 16), f3 = __uint_as_float(r.y & 0xffff0000u);
        float f4 = __uint_as_float(r.z << 16), f5 = __uint_as_float(r.z & 0xffff0000u);
        float f6 = __uint_as_float(r.w << 16), f7 = __uint_as_float(r.w & 0xffff0000u);
        float4* d = (float4*)&qs[h * AW + c];
        d[0] = make_float4(f0, f1, f2, f3);
        d[1] = make_float4(f4, f5, f6, f7);
    }
#pragma unroll
    for (int it = 0; it < 4; it++) {
        int vi = lane + 64 * it;          // 0..255
        int g = vi >> 5, c = (vi & 31) * 8;   // 0..248
        uint4 r = *(const uint4*)(kvrow + vi * 8);
        float f0 = __uint_as_float(r.x << 16), f1 = __uint_as_float(r.x & 0xffff0000u);
        float f2 = __uint_as_float(r.y << 16), f3 = __uint_as_float(r.y & 0xffff0000u);
        float f4 = __uint_as_float(r.z << 16), f5 = __uint_as_float(r.z & 0xffff0000u);
        float f6 = __uint_as_float(r.w << 16), f7 = __uint_as_float(r.w & 0xffff0000u);
        float* base = (c < 128) ? &ks[g * AW + c] : &vs[g * AW + (c - 128)];
        ((float4*)base)[0] = make_float4(f0, f1, f2, f3);
        ((float4*)base)[1] = make_float4(f4, f5, f6, f7);
    }
    __syncthreads();

    // scores: lane = h*8+g
    const int h = lane >> 3, g = lane & 7;
    float s = 0.f;
#pragma unroll 8
    for (int d = 0; d < 128; d += 4) {
        float4 qv = *(const float4*)&qs[h * AW + d];
        float4 kv = *(const float4*)&ks[g * AW + d];
        s += qv.x * kv.x + qv.y * kv.y + qv.z * kv.z + qv.w * kv.w;
    }
    s *= 0.08838834764831845f;   // 1/sqrt(128)
    float m = s;
    m = fmaxf(m, __shfl_xor(m, 1, 64));
    m = fmaxf(m, __shfl_xor(m, 2, 64));
    m = fmaxf(m, __shfl_xor(m, 4, 64));
    float p = __expf(s - m);
    float sum = p;
    sum += __shfl_xor(sum, 1, 64);
    sum += __shfl_xor(sum, 2, 64);
    sum += __shfl_xor(sum, 4, 64);
    ws[lane] = p / sum;
    __syncthreads();

    // PV: lane owns (h = lane>>3, 16-col slab db = lane&7)
    const int db = lane & 7;
    float o[16];
#pragma unroll
    for (int j = 0; j < 16; j++) o[j] = 0.f;
#pragma unroll
    for (int g2 = 0; g2 < 8; g2++) {
        float wv = ws[h * 8 + g2];
        const float* vr = &vs[g2 * AW + db * 16];
#pragma unroll
        for (int j = 0; j < 16; j++) o[j] += wv * vr[j];
    }
    u16* orow = O + pos * qstride + h * 128 + db * 16;
    u32 pk[8];
#pragma unroll
    for (int j = 0; j < 8; j++)
        pk[j] = (u32)f2bf(o[2 * j]) | ((u32)f2bf(o[2 * j + 1]) << 16);
    ((uint4*)orow)[0] = make_uint4(pk[0], pk[1], pk[2], pk[3]);
    ((uint4*)orow)[1] = make_uint4(pk[4], pk[5], pk[6], pk[7]);
}

// src f32 (K,N) row-major -> dst bf16 (N,K) row-major
__global__ __launch_bounds__(256) void transpose_f32_bf16(
    const float* __restrict__ src, u16* __restrict__ dst, int K, int N)
{
    __shared__ float tile[32][33];
    const int tx = threadIdx.x & 31, ty = threadIdx.x >> 5;
    const int c0 = blockIdx.x * 32, r0 = blockIdx.y * 32;
#pragma unroll
    for (int i = 0; i < 4; i++)
        tile[ty + i * 8][tx] = src[(size_t)(r0 + ty + i * 8) * N + c0 + tx];
    __syncthreads();
#pragma unroll
    for (int i = 0; i < 4; i++)
        dst[(size_t)(c0 + ty + i * 8) * K + r0 + tx] = f2bf(tile[tx][ty + i * 8]);
}

extern "C" void kernel_launch(void* const* d_in, const int* in_sizes, int n_in,
                              void* d_out, int out_size, void* d_ws, size_t ws_size,
                              hipStream_t stream) {
    const float* liquid = (const float*)d_in[0];
    const float* mamba  = (const float*)d_in[1];
    const float* Wlq  = (const float*)d_in[2];
    const float* blq  = (const float*)d_in[3];
    const float* Wmkv = (const float*)d_in[4];
    const float* bmkv = (const float*)d_in[5];
    const float* Wmq  = (const float*)d_in[6];
    const float* bmq  = (const float*)d_in[7];
    const float* Wlkv = (const float*)d_in[8];
    const float* blkv = (const float*)d_in[9];
    const float* Wlo  = (const float*)d_in[10];
    const float* blo  = (const float*)d_in[11];
    const float* Wmo  = (const float*)d_in[12];
    const float* bmo  = (const float*)d_in[13];
    float* out = (float*)d_out;   // [enhanced_liquid | enhanced_mamba], each 32768x1024 fp32

    // workspace carve (bf16)
    u16* p = (u16*)d_ws;
    u16* WtLq  = p; p += (size_t)1024 * 1024;
    u16* WtLkv = p; p += (size_t)2048 * 1024;
    u16* WtMq  = p; p += (size_t)1024 * 1024;
    u16* WtMkv = p; p += (size_t)2048 * 1024;
    u16* WtLo  = p; p += (size_t)1024 * 1024;
    u16* WtMo  = p; p += (size_t)1024 * 1024;
    u16* Q  = p; p += (size_t)32768 * 1024;   // q_l -> a_l, then reused for q_m -> a_m
    u16* KV = p;                              // kv_m, then reused for kv_l

    // bf16 activations in second half of d_out (only written by the final GEMM,
    // strictly after their last read — stream-ordered, no race)
    u16* Lb = (u16*)(out + (size_t)32768 * 1024);          // 64 MB
    u16* Mb = Lb + (size_t)32768 * 1024;                   // 64 MB

    transpose_f32_bf16<<<dim3(32, 32), 256, 0, stream>>>(Wlq,  WtLq,  1024, 1024);
    transpose_f32_bf16<<<dim3(64, 32), 256, 0, stream>>>(Wlkv, WtLkv, 1024, 2048);
    transpose_f32_bf16<<<dim3(32, 32), 256, 0, stream>>>(Wmq,  WtMq,  1024, 1024);
    transpose_f32_bf16<<<dim3(64, 32), 256, 0, stream>>>(Wmkv, WtMkv, 1024, 2048);
    transpose_f32_bf16<<<dim3(32, 32), 256, 0, stream>>>(Wlo,  WtLo,  1024, 1024);
    transpose_f32_bf16<<<dim3(32, 32), 256, 0, stream>>>(Wmo,  WtMo,  1024, 1024);

    convert_f32_bf16<<<16384, 256, 0, stream>>>(liquid, Lb);
    convert_f32_bf16<<<16384, 256, 0, stream>>>(mamba,  Mb);

    // ---- phase L: enhanced_liquid ----
    gemm_a16_c16<<<dim3(256, 8),  256, 0, stream>>>(Lb, 1024, WtLq,  blq,  Q,  1024, 1024);
    gemm_a16_c16<<<dim3(256, 16), 256, 0, stream>>>(Mb, 1024, WtMkv, bmkv, KV, 2048, 1024);
    attn8<<<8192, 256, 0, stream>>>(Q, KV, Q, 1024, 2048);
    gemm_a16_c32<<<dim3(256, 8),  256, 0, stream>>>(Q, 1024, WtLo, blo, liquid, 1024,
                                                    out, 1024, 1024);

    // ---- phase M: enhanced_mamba ----
    gemm_a16_c16<<<dim3(256, 8),  256, 0, stream>>>(Mb, 1024, WtMq,  bmq,  Q,  1024, 1024);
    gemm_a16_c16<<<dim3(256, 16), 256, 0, stream>>>(Lb, 1024, WtLkv, blkv, KV, 2048, 1024);
    attn8<<<8192, 256, 0, stream>>>(Q, KV, Q, 1024, 2048);
    gemm_a16_c32<<<dim3(256, 8),  256, 0, stream>>>(Q, 1024, WtMo, bmo, mamba, 1024,
                                                    out + (size_t)32768 * 1024, 1024, 1024);
}